// Round 3
// baseline (336.007 us; speedup 1.0000x reference)
//
#include <hip/hip_runtime.h>
#include <stdint.h>

#define Ttok 1024
#define Hdim 2048
#define Idim 1024
#define Enum 16

typedef __attribute__((ext_vector_type(8))) short  short8;
typedef __attribute__((ext_vector_type(4))) short  short4v;
typedef __attribute__((ext_vector_type(4))) float  f32x4;

__device__ __forceinline__ unsigned short f2bf(float f) {
    union { float f; uint32_t u; } v; v.f = f;
    uint32_t u = v.u;
    return (unsigned short)((u + 0x7FFFu + ((u >> 16) & 1u)) >> 16);
}

__device__ __forceinline__ void gld_lds16(const void* g, void* l) {
    __builtin_amdgcn_global_load_lds(
        (const __attribute__((address_space(1))) unsigned int*)g,
        (__attribute__((address_space(3))) unsigned int*)l, 16, 0, 0);
}

__device__ __forceinline__ int prefix_chunks(const int* counts, int e) {
    int p = 0;
    for (int j = 0; j < e; ++j) p += (counts[j] + 63) >> 6;
    return p;
}

// ---------------- Router: logits -> softmax -> biased top2 -> scatter ----------------
__global__ __launch_bounds__(256) void k_router(
    const float* __restrict__ x, const float* __restrict__ gw,
    const float* __restrict__ bias,
    int* __restrict__ counts, int* __restrict__ tids, float* __restrict__ tws)
{
    __shared__ __align__(16) float xrow[Hdim];
    __shared__ float lg[Enum];
    const int t = blockIdx.x;
    const float* xr = x + (size_t)t * Hdim;

    for (int i = threadIdx.x; i < Hdim / 4; i += 256)
        ((f32x4*)xrow)[i] = ((const f32x4*)xr)[i];
    __syncthreads();

    const int lane = threadIdx.x & 63;
    const int wid  = threadIdx.x >> 6;
    for (int e = wid; e < Enum; e += 4) {
        const float* g = gw + (size_t)e * Hdim;
        float s = 0.f;
        for (int j = lane; j < Hdim; j += 64) s += xrow[j] * g[j];
        #pragma unroll
        for (int off = 32; off; off >>= 1) s += __shfl_xor(s, off);
        if (lane == 0) lg[e] = s;
    }
    __syncthreads();

    if (threadIdx.x == 0) {
        float m = lg[0];
        #pragma unroll
        for (int e = 1; e < Enum; ++e) m = fmaxf(m, lg[e]);
        float sc[Enum]; float sum = 0.f;
        #pragma unroll
        for (int e = 0; e < Enum; ++e) { float ex = expf(lg[e] - m); sc[e] = ex; sum += ex; }
        float inv = 1.f / sum;
        #pragma unroll
        for (int e = 0; e < Enum; ++e) sc[e] *= inv;
        int i0 = 0; float b0 = sc[0] + bias[0];
        #pragma unroll
        for (int e = 1; e < Enum; ++e) { float bb = sc[e] + bias[e]; if (bb > b0) { b0 = bb; i0 = e; } }
        int i1 = -1; float b1 = -1e30f;
        #pragma unroll
        for (int e = 0; e < Enum; ++e) {
            if (e == i0) continue;
            float bb = sc[e] + bias[e]; if (bb > b1) { b1 = bb; i1 = e; }
        }
        float w0 = sc[i0], w1v = sc[i1];
        float winv = 1.f / (w0 + w1v);
        w0 *= winv; w1v *= winv;
        int p0 = atomicAdd(&counts[i0], 1);
        tids[i0 * Ttok + p0] = t; tws[i0 * Ttok + p0] = w0;
        int p1 = atomicAdd(&counts[i1], 1);
        tids[i1 * Ttok + p1] = t; tws[i1 * Ttok + p1] = w1v;
    }
}

// ---------------- Gather: compact + transpose X into tile layout ----------------
// Xg element (chunk q, kg 0..255, row 0..63, h 0..7) at ((q*256+kg)*64+row)*8+h.
// Pad rows (>=Ne) are zero-filled.
__global__ __launch_bounds__(256) void k_gather(
    const float* __restrict__ x, const int* __restrict__ counts,
    const int* __restrict__ tids, unsigned short* __restrict__ Xg)
{
    const int e = blockIdx.y, c = blockIdx.x;
    const int Ne = counts[e];
    const int NC = (Ne + 63) >> 6;
    if (c >= NC) return;
    const int poff = prefix_chunks(counts, e);
    unsigned short* dst = Xg + ((size_t)(poff + c) * 256 + threadIdx.x) * 512;
    const int rbase = c * 64;
    for (int rl = 0; rl < 64; ++rl) {
        int r = rbase + rl;
        short8 v = (short8)0;
        if (r < Ne) {
            int tok = tids[e * Ttok + r];
            f32x4 p0 = ((const f32x4*)x)[(size_t)tok * 512 + threadIdx.x * 2];
            f32x4 p1 = ((const f32x4*)x)[(size_t)tok * 512 + threadIdx.x * 2 + 1];
            v[0] = (short)f2bf(p0[0]); v[1] = (short)f2bf(p0[1]);
            v[2] = (short)f2bf(p0[2]); v[3] = (short)f2bf(p0[3]);
            v[4] = (short)f2bf(p1[0]); v[5] = (short)f2bf(p1[1]);
            v[6] = (short)f2bf(p1[2]); v[7] = (short)f2bf(p1[3]);
        }
        *(short8*)(dst + rl * 8) = v;
    }
}

// ---------------- Stage 2: He = silu(X@W1) * (X@W3) ----------------
// grid (Idim/32=32, 8, Enum), block 512 (8 waves: mat = wid>>2, rowq = wid&3).
union ShH {
    struct { unsigned short Xs[2][8][128][8]; unsigned short Ws[2][2][8][32][8]; } a; // 32K+16K
    struct { float T1[128][33]; float T3[128][33]; } b;                               // 33.8K
};

__global__ __launch_bounds__(512) void k_expert_h(
    const unsigned short* __restrict__ Xg,
    const float* __restrict__ w1, const float* __restrict__ w3,
    const int* __restrict__ counts,
    unsigned short* __restrict__ He)
{
    const int e = blockIdx.z;
    const int Ne = counts[e];
    const int row0 = blockIdx.y * 128;
    if (row0 >= Ne) return;
    const int NC   = (Ne + 63) >> 6;
    const int poff = prefix_chunks(counts, e);
    const int c0   = blockIdx.y * 2;
    const int col0 = blockIdx.x * 32;
    const int tid  = threadIdx.x;
    const int lane = tid & 63;
    const int wid  = tid >> 6;

    __shared__ ShH sh;

    // X staging sources: wave wid stages kgrp=wid of both row-chunks (clamped)
    const unsigned short* xsrc[2];
    #pragma unroll
    for (int cc = 0; cc < 2; ++cc) {
        int q = c0 + cc; if (q > NC - 1) q = NC - 1;
        xsrc[cc] = Xg + ((size_t)(poff + q) * 256 + wid) * 512 + lane * 8;
    }
    // W staging: bits tid[8]=mat, tid[7]=khalf, tid[6:4]=kg, tid[3:0]=colpair
    const int wm  = (tid >> 8) & 1;
    const int wkh = (tid >> 7) & 1;
    const int wkg = (tid >> 4) & 7;
    const int wcp = tid & 15;
    const float* wsrc = (wm ? w3 : w1)
        + ((size_t)e * Hdim + wkg * 8 + wkh * 4) * Idim + col0 + wcp * 2;

    const int m  = wid >> 2;
    const int rq = wid & 3;

    f32x4 acc[2][2];
    #pragma unroll
    for (int a = 0; a < 2; ++a)
        #pragma unroll
        for (int b = 0; b < 2; ++b) acc[a][b] = (f32x4)(0.f);

    const int NK = Hdim / 64; // 32

    { // prologue -> buf 0
        float2 wv[4];
        #pragma unroll
        for (int jj = 0; jj < 4; ++jj) wv[jj] = *(const float2*)(wsrc + (size_t)jj * Idim);
        #pragma unroll
        for (int cc = 0; cc < 2; ++cc)
            gld_lds16(xsrc[cc], &sh.a.Xs[0][wid][cc * 64][0]);
        short4v pa, pb;
        #pragma unroll
        for (int jj = 0; jj < 4; ++jj) { pa[jj] = (short)f2bf(wv[jj].x); pb[jj] = (short)f2bf(wv[jj].y); }
        *(short4v*)&sh.a.Ws[0][wm][wkg][wcp * 2][wkh * 4]     = pa;
        *(short4v*)&sh.a.Ws[0][wm][wkg][wcp * 2 + 1][wkh * 4] = pb;
    }
    __syncthreads();

    for (int ks = 0; ks < NK; ++ks) {
        const int cur = ks & 1, nxt = cur ^ 1;
        float2 wv[4];
        if (ks + 1 < NK) {
            const float* wp = wsrc + (size_t)(ks + 1) * 64 * Idim;
            #pragma unroll
            for (int jj = 0; jj < 4; ++jj) wv[jj] = *(const float2*)(wp + (size_t)jj * Idim);
            #pragma unroll
            for (int cc = 0; cc < 2; ++cc)
                gld_lds16(xsrc[cc] + (size_t)(ks + 1) * 4096, &sh.a.Xs[nxt][wid][cc * 64][0]);
        }
        #pragma unroll
        for (int ks2 = 0; ks2 < 2; ++ks2) {
            const int kgi = ks2 * 4 + (lane >> 4);
            short8 a0 = *(const short8*)&sh.a.Xs[cur][kgi][rq * 32 + (lane & 15)][0];
            short8 a1 = *(const short8*)&sh.a.Xs[cur][kgi][rq * 32 + 16 + (lane & 15)][0];
            short8 b0 = *(const short8*)&sh.a.Ws[cur][m][kgi][(lane & 15)][0];
            short8 b1 = *(const short8*)&sh.a.Ws[cur][m][kgi][16 + (lane & 15)][0];
            acc[0][0] = __builtin_amdgcn_mfma_f32_16x16x32_bf16(a0, b0, acc[0][0], 0, 0, 0);
            acc[0][1] = __builtin_amdgcn_mfma_f32_16x16x32_bf16(a0, b1, acc[0][1], 0, 0, 0);
            acc[1][0] = __builtin_amdgcn_mfma_f32_16x16x32_bf16(a1, b0, acc[1][0], 0, 0, 0);
            acc[1][1] = __builtin_amdgcn_mfma_f32_16x16x32_bf16(a1, b1, acc[1][1], 0, 0, 0);
        }
        if (ks + 1 < NK) {
            short4v pa, pb;
            #pragma unroll
            for (int jj = 0; jj < 4; ++jj) { pa[jj] = (short)f2bf(wv[jj].x); pb[jj] = (short)f2bf(wv[jj].y); }
            *(short4v*)&sh.a.Ws[nxt][wm][wkg][wcp * 2][wkh * 4]     = pa;
            *(short4v*)&sh.a.Ws[nxt][wm][wkg][wcp * 2 + 1][wkh * 4] = pb;
        }
        __syncthreads();
    }

    // epilogue: bounce acc through LDS, fuse silu, write He transposed tiles
    {
        float (*T)[33] = m ? sh.b.T3 : sh.b.T1;
        #pragma unroll
        for (int fr = 0; fr < 2; ++fr)
            #pragma unroll
            for (int fc = 0; fc < 2; ++fc)
                #pragma unroll
                for (int k = 0; k < 4; ++k) {
                    int row = rq * 32 + fr * 16 + ((lane >> 4) << 2) + k;
                    int col = fc * 16 + (lane & 15);
                    T[row][col] = acc[fr][fc][k];
                }
    }
    __syncthreads();
    {
        const int cc = tid >> 8, cg = (tid >> 6) & 3, rl = tid & 63;
        if (c0 + cc < NC) {
            short8 o;
            #pragma unroll
            for (int hh = 0; hh < 8; ++hh) {
                float h1 = sh.b.T1[cc * 64 + rl][cg * 8 + hh];
                float h3 = sh.b.T3[cc * 64 + rl][cg * 8 + hh];
                float he = h1 * h3 / (1.f + expf(-h1));
                o[hh] = (short)f2bf(he);
            }
            *(short8*)(He + ((size_t)(poff + c0 + cc) * 128 + blockIdx.x * 4 + cg) * 512 + rl * 8) = o;
        }
    }
}

// ---------------- Stage 3: out += w * (He @ W2) ----------------
// grid (Hdim/32=64, 8, Enum), block 256 (4 waves).
__global__ __launch_bounds__(256) void k_expert_o(
    const unsigned short* __restrict__ He,
    const float* __restrict__ w2,
    const int* __restrict__ counts, const int* __restrict__ tids,
    const float* __restrict__ tws,
    float* __restrict__ out)
{
    const int e = blockIdx.z;
    const int Ne = counts[e];
    const int row0 = blockIdx.y * 128;
    if (row0 >= Ne) return;
    const int NC   = (Ne + 63) >> 6;
    const int poff = prefix_chunks(counts, e);
    const int c0   = blockIdx.y * 2;
    const int col0 = blockIdx.x * 32;
    const int tid  = threadIdx.x;
    const int lane = tid & 63;
    const int wid  = tid >> 6;

    __shared__ __align__(16) unsigned short Hs[2][8][128][8];  // 32 KB
    __shared__ __align__(16) unsigned short W2s[2][8][32][8];  // 8 KB

    // He staging: wave wid stages kgrps {2wid, 2wid+1} of both chunks
    const unsigned short* hsrc[2][2];
    #pragma unroll
    for (int cc = 0; cc < 2; ++cc) {
        int q = c0 + cc; if (q > NC - 1) q = NC - 1;
        #pragma unroll
        for (int kk = 0; kk < 2; ++kk)
            hsrc[cc][kk] = He + ((size_t)(poff + q) * 128 + wid * 2 + kk) * 512 + lane * 8;
    }
    const int wkh = (tid >> 7) & 1;
    const int wkg = (tid >> 4) & 7;
    const int wcp = tid & 15;
    const float* wsrc = w2 + ((size_t)e * Idim + wkg * 8 + wkh * 4) * Hdim + col0 + wcp * 2;

    f32x4 acc[2][2];
    #pragma unroll
    for (int a = 0; a < 2; ++a)
        #pragma unroll
        for (int b = 0; b < 2; ++b) acc[a][b] = (f32x4)(0.f);

    const int NK = Idim / 64; // 16
    { // prologue
        float2 wv[4];
        #pragma unroll
        for (int jj = 0; jj < 4; ++jj) wv[jj] = *(const float2*)(wsrc + (size_t)jj * Hdim);
        #pragma unroll
        for (int cc = 0; cc < 2; ++cc)
            #pragma unroll
            for (int kk = 0; kk < 2; ++kk)
                gld_lds16(hsrc[cc][kk], &Hs[0][wid * 2 + kk][cc * 64][0]);
        short4v pa, pb;
        #pragma unroll
        for (int jj = 0; jj < 4; ++jj) { pa[jj] = (short)f2bf(wv[jj].x); pb[jj] = (short)f2bf(wv[jj].y); }
        *(short4v*)&W2s[0][wkg][wcp * 2][wkh * 4]     = pa;
        *(short4v*)&W2s[0][wkg][wcp * 2 + 1][wkh * 4] = pb;
    }
    __syncthreads();

    for (int ks = 0; ks < NK; ++ks) {
        const int cur = ks & 1, nxt = cur ^ 1;
        float2 wv[4];
        if (ks + 1 < NK) {
            const float* wp = wsrc + (size_t)(ks + 1) * 64 * Hdim;
            #pragma unroll
            for (int jj = 0; jj < 4; ++jj) wv[jj] = *(const float2*)(wp + (size_t)jj * Hdim);
            #pragma unroll
            for (int cc = 0; cc < 2; ++cc)
                #pragma unroll
                for (int kk = 0; kk < 2; ++kk)
                    gld_lds16(hsrc[cc][kk] + (size_t)(ks + 1) * 4096,
                              &Hs[nxt][wid * 2 + kk][cc * 64][0]);
        }
        #pragma unroll
        for (int ks2 = 0; ks2 < 2; ++ks2) {
            const int kgi = ks2 * 4 + (lane >> 4);
            short8 a0 = *(const short8*)&Hs[cur][kgi][wid * 32 + (lane & 15)][0];
            short8 a1 = *(const short8*)&Hs[cur][kgi][wid * 32 + 16 + (lane & 15)][0];
            short8 b0 = *(const short8*)&W2s[cur][kgi][(lane & 15)][0];
            short8 b1 = *(const short8*)&W2s[cur][kgi][16 + (lane & 15)][0];
            acc[0][0] = __builtin_amdgcn_mfma_f32_16x16x32_bf16(a0, b0, acc[0][0], 0, 0, 0);
            acc[0][1] = __builtin_amdgcn_mfma_f32_16x16x32_bf16(a0, b1, acc[0][1], 0, 0, 0);
            acc[1][0] = __builtin_amdgcn_mfma_f32_16x16x32_bf16(a1, b0, acc[1][0], 0, 0, 0);
            acc[1][1] = __builtin_amdgcn_mfma_f32_16x16x32_bf16(a1, b1, acc[1][1], 0, 0, 0);
        }
        if (ks + 1 < NK) {
            short4v pa, pb;
            #pragma unroll
            for (int jj = 0; jj < 4; ++jj) { pa[jj] = (short)f2bf(wv[jj].x); pb[jj] = (short)f2bf(wv[jj].y); }
            *(short4v*)&W2s[nxt][wkg][wcp * 2][wkh * 4]     = pa;
            *(short4v*)&W2s[nxt][wkg][wcp * 2 + 1][wkh * 4] = pb;
        }
        __syncthreads();
    }

    #pragma unroll
    for (int fr = 0; fr < 2; ++fr) {
        #pragma unroll
        for (int k = 0; k < 4; ++k) {
            int grow = row0 + wid * 32 + fr * 16 + ((lane >> 4) << 2) + k;
            if (grow < Ne) {
                int   tk = tids[e * Ttok + grow];
                float w  = tws[e * Ttok + grow];
                #pragma unroll
                for (int fc = 0; fc < 2; ++fc) {
                    int col = col0 + fc * 16 + (lane & 15);
                    atomicAdd(&out[(size_t)tk * Hdim + col], w * acc[fr][fc][k]);
                }
            }
        }
    }
}

extern "C" void kernel_launch(void* const* d_in, const int* in_sizes, int n_in,
                              void* d_out, int out_size, void* d_ws, size_t ws_size,
                              hipStream_t stream)
{
    const float* x    = (const float*)d_in[0];
    const float* gw   = (const float*)d_in[1];
    const float* bias = (const float*)d_in[2];
    const float* w1   = (const float*)d_in[3];
    const float* w3   = (const float*)d_in[4];
    const float* w2   = (const float*)d_in[5];
    float* out = (float*)d_out;

    char* ws = (char*)d_ws;
    int*            counts = (int*)ws;                         // @0      (64 B)
    int*            tids   = (int*)(ws + 1024);                // @1K     (64 KB)
    float*          tws    = (float*)(ws + 66560);             // @65K    (64 KB)
    unsigned short* Xg     = (unsigned short*)(ws + 132096);   // 12 MB max (48 chunks x 256 KB)
    unsigned short* He     = (unsigned short*)(ws + 12715008); // 6 MB max  (48 chunks x 128 KB)

    hipMemsetAsync(counts, 0, Enum * sizeof(int), stream);
    hipMemsetAsync(out, 0, (size_t)Ttok * Hdim * sizeof(float), stream);

    k_router<<<dim3(Ttok), dim3(256), 0, stream>>>(x, gw, bias, counts, tids, tws);
    k_gather<<<dim3(16, Enum), dim3(256), 0, stream>>>(x, counts, tids, Xg);
    k_expert_h<<<dim3(Idim / 32, 8, Enum), dim3(512), 0, stream>>>(Xg, w1, w3, counts, He);
    k_expert_o<<<dim3(Hdim / 32, 8, Enum), dim3(256), 0, stream>>>(He, w2, counts, tids, tws, out);
}

// Round 4
// 293.448 us; speedup vs baseline: 1.1450x; 1.1450x over previous
//
#include <hip/hip_runtime.h>
#include <stdint.h>

#define Ttok 1024
#define Hdim 2048
#define Idim 1024
#define Enum 16

typedef __attribute__((ext_vector_type(8))) short  short8;
typedef __attribute__((ext_vector_type(4))) float  f32x4;

__device__ __forceinline__ unsigned short f2bf(float f) {
    union { float f; uint32_t u; } v; v.f = f;
    uint32_t u = v.u;
    return (unsigned short)((u + 0x7FFFu + ((u >> 16) & 1u)) >> 16);
}

__device__ __forceinline__ void gld_lds16(const void* g, void* l) {
    __builtin_amdgcn_global_load_lds(
        (const __attribute__((address_space(1))) unsigned int*)g,
        (__attribute__((address_space(3))) unsigned int*)l, 16, 0, 0);
}

// ---------------- Router: logits -> softmax -> biased top2 -> scatter + x->bf16 ----------------
__global__ __launch_bounds__(256) void k_router(
    const float* __restrict__ x, const float* __restrict__ gw,
    const float* __restrict__ bias,
    unsigned short* __restrict__ xbf, int* __restrict__ counts,
    int* __restrict__ tids, float* __restrict__ tws)
{
    __shared__ __align__(16) float xrow[Hdim];
    __shared__ float lg[Enum];
    const int t = blockIdx.x;
    const float* xr = x + (size_t)t * Hdim;
    unsigned short* xb = xbf + (size_t)t * Hdim;

    for (int i = threadIdx.x; i < Hdim / 4; i += 256) {
        f32x4 v = ((const f32x4*)xr)[i];
        ((f32x4*)xrow)[i] = v;
        ushort4 b;
        b.x = f2bf(v.x); b.y = f2bf(v.y); b.z = f2bf(v.z); b.w = f2bf(v.w);
        ((ushort4*)xb)[i] = b;
    }
    __syncthreads();

    const int lane = threadIdx.x & 63;
    const int wid  = threadIdx.x >> 6;
    for (int e = wid; e < Enum; e += 4) {
        const float* g = gw + (size_t)e * Hdim;
        float s = 0.f;
        for (int j = lane; j < Hdim; j += 64) s += xrow[j] * g[j];
        #pragma unroll
        for (int off = 32; off; off >>= 1) s += __shfl_xor(s, off);
        if (lane == 0) lg[e] = s;
    }
    __syncthreads();

    if (threadIdx.x == 0) {
        float m = lg[0];
        #pragma unroll
        for (int e = 1; e < Enum; ++e) m = fmaxf(m, lg[e]);
        float sc[Enum]; float sum = 0.f;
        #pragma unroll
        for (int e = 0; e < Enum; ++e) { float ex = expf(lg[e] - m); sc[e] = ex; sum += ex; }
        float inv = 1.f / sum;
        #pragma unroll
        for (int e = 0; e < Enum; ++e) sc[e] *= inv;
        int i0 = 0; float b0 = sc[0] + bias[0];
        #pragma unroll
        for (int e = 1; e < Enum; ++e) { float bb = sc[e] + bias[e]; if (bb > b0) { b0 = bb; i0 = e; } }
        int i1 = -1; float b1 = -1e30f;
        #pragma unroll
        for (int e = 0; e < Enum; ++e) {
            if (e == i0) continue;
            float bb = sc[e] + bias[e]; if (bb > b1) { b1 = bb; i1 = e; }
        }
        float w0 = sc[i0], w1v = sc[i1];
        float winv = 1.f / (w0 + w1v);
        w0 *= winv; w1v *= winv;
        int p0 = atomicAdd(&counts[i0], 1);
        tids[i0 * Ttok + p0] = t; tws[i0 * Ttok + p0] = w0;
        int p1 = atomicAdd(&counts[i1], 1);
        tids[i1 * Ttok + p1] = t; tws[i1 * Ttok + p1] = w1v;
    }
}

// ---------------- Stage 2: He = silu(X@W1) * (X@W3) ----------------
// grid (Idim/32=32, 16 chunks, Enum), block 256 (4 waves: m=wid>>1, rh=wid&1)
// BM=64 (one chunk), BN=32 per mat, BK=64.
union ShH {
    struct {
        unsigned short Xs[2][8][64][8];     // 16 KB [buf][kg][row][8]
        unsigned short Ws[2][2][8][32][8];  // 16 KB [buf][mat][kg][col][8]
    } a;
    struct { float T1[64][33]; float T3[64][33]; } b;  // 16.9 KB
};

__global__ __launch_bounds__(256) void k_expert_h(
    const unsigned short* __restrict__ xbf,
    const float* __restrict__ w1, const float* __restrict__ w3,
    const int* __restrict__ counts, const int* __restrict__ tids,
    unsigned short* __restrict__ He)
{
    const int e  = blockIdx.z;
    const int Ne = counts[e];
    const int c  = blockIdx.y;
    if (c * 64 >= Ne) return;
    int poff = 0;
    #pragma unroll
    for (int j = 0; j < Enum; ++j) if (j < e) poff += (counts[j] + 63) >> 6;
    const int col0 = blockIdx.x * 32;
    const int tid  = threadIdx.x;
    const int lane = tid & 63;
    const int wid  = tid >> 6;

    __shared__ ShH sh;

    // X gather source: row = c*64 + lane (clamped), wave wid stages kg {2wid, 2wid+1}
    int r  = c * 64 + lane;
    int tk = (r < Ne) ? tids[e * Ttok + r] : tids[e * Ttok];
    const unsigned short* xsrc = xbf + (size_t)tk * Hdim + wid * 16;

    // W staging: mat = tid>>7, kg = (tid>>4)&7, colpair = tid&15
    const int wm  = tid >> 7;
    const int wkg = (tid >> 4) & 7;
    const int wcp = tid & 15;
    const float* wsrc = (wm ? w3 : w1) + ((size_t)e * Hdim + wkg * 8) * Idim + col0 + wcp * 2;

    const int m  = wid >> 1;   // this wave's mat (0=W1, 1=W3)
    const int rh = wid & 1;    // row half (32 rows)

    f32x4 acc[2][2];
    #pragma unroll
    for (int a = 0; a < 2; ++a)
        #pragma unroll
        for (int b = 0; b < 2; ++b) acc[a][b] = (f32x4)(0.f);

    const int NK = Hdim / 64; // 32
    float2 wv[8];
    { // prologue -> buf 0
        #pragma unroll
        for (int kk = 0; kk < 2; ++kk)
            gld_lds16(xsrc + kk * 8, &sh.a.Xs[0][wid * 2 + kk][0][0]);
        #pragma unroll
        for (int j = 0; j < 8; ++j) wv[j] = *(const float2*)(wsrc + (size_t)j * Idim);
        short8 p0, p1;
        #pragma unroll
        for (int j = 0; j < 8; ++j) { p0[j] = (short)f2bf(wv[j].x); p1[j] = (short)f2bf(wv[j].y); }
        *(short8*)&sh.a.Ws[0][wm][wkg][wcp * 2][0]     = p0;
        *(short8*)&sh.a.Ws[0][wm][wkg][wcp * 2 + 1][0] = p1;
    }
    __syncthreads();

    for (int ks = 0; ks < NK; ++ks) {
        const int cur = ks & 1, nxt = cur ^ 1;
        if (ks + 1 < NK) {
            #pragma unroll
            for (int kk = 0; kk < 2; ++kk)
                gld_lds16(xsrc + (size_t)(ks + 1) * 64 + kk * 8,
                          &sh.a.Xs[nxt][wid * 2 + kk][0][0]);
            const float* wp = wsrc + (size_t)(ks + 1) * 64 * Idim;
            #pragma unroll
            for (int j = 0; j < 8; ++j) wv[j] = *(const float2*)(wp + (size_t)j * Idim);
        }
        #pragma unroll
        for (int ks2 = 0; ks2 < 2; ++ks2) {
            const int kgi = ks2 * 4 + (lane >> 4);
            short8 a0 = *(const short8*)&sh.a.Xs[cur][kgi][rh * 32 + (lane & 15)][0];
            short8 a1 = *(const short8*)&sh.a.Xs[cur][kgi][rh * 32 + 16 + (lane & 15)][0];
            short8 b0 = *(const short8*)&sh.a.Ws[cur][m][kgi][(lane & 15)][0];
            short8 b1 = *(const short8*)&sh.a.Ws[cur][m][kgi][16 + (lane & 15)][0];
            acc[0][0] = __builtin_amdgcn_mfma_f32_16x16x32_bf16(a0, b0, acc[0][0], 0, 0, 0);
            acc[0][1] = __builtin_amdgcn_mfma_f32_16x16x32_bf16(a0, b1, acc[0][1], 0, 0, 0);
            acc[1][0] = __builtin_amdgcn_mfma_f32_16x16x32_bf16(a1, b0, acc[1][0], 0, 0, 0);
            acc[1][1] = __builtin_amdgcn_mfma_f32_16x16x32_bf16(a1, b1, acc[1][1], 0, 0, 0);
        }
        if (ks + 1 < NK) {
            short8 p0, p1;
            #pragma unroll
            for (int j = 0; j < 8; ++j) { p0[j] = (short)f2bf(wv[j].x); p1[j] = (short)f2bf(wv[j].y); }
            *(short8*)&sh.a.Ws[nxt][wm][wkg][wcp * 2][0]     = p0;
            *(short8*)&sh.a.Ws[nxt][wm][wkg][wcp * 2 + 1][0] = p1;
        }
        __syncthreads();
    }

    // epilogue: bounce acc through LDS (union reuse is safe: all frag reads done)
    {
        float (*T)[33] = m ? sh.b.T3 : sh.b.T1;
        #pragma unroll
        for (int fr = 0; fr < 2; ++fr)
            #pragma unroll
            for (int fc = 0; fc < 2; ++fc)
                #pragma unroll
                for (int k = 0; k < 4; ++k) {
                    int row = rh * 32 + fr * 16 + ((lane >> 4) << 2) + k;
                    int col = fc * 16 + (lane & 15);
                    T[row][col] = acc[fr][fc][k];
                }
    }
    __syncthreads();
    {
        const int cg = tid >> 6, rl = tid & 63;
        short8 o;
        #pragma unroll
        for (int hh = 0; hh < 8; ++hh) {
            float h1 = sh.b.T1[rl][cg * 8 + hh];
            float h3 = sh.b.T3[rl][cg * 8 + hh];
            float he = h1 * h3 / (1.f + expf(-h1));
            o[hh] = (short)f2bf(he);
        }
        *(short8*)(He + ((size_t)(poff + c) * 128 + blockIdx.x * 4 + cg) * 512 + rl * 8) = o;
    }
}

// ---------------- Stage 3: out += w * (He @ W2) ----------------
// grid (Hdim/32=64, 16 chunks, Enum), block 256 (4 waves; wave wid: rows wid*16)
__global__ __launch_bounds__(256) void k_expert_o(
    const unsigned short* __restrict__ He,
    const float* __restrict__ w2,
    const int* __restrict__ counts, const int* __restrict__ tids,
    const float* __restrict__ tws,
    float* __restrict__ out)
{
    const int e  = blockIdx.z;
    const int Ne = counts[e];
    const int c  = blockIdx.y;
    if (c * 64 >= Ne) return;
    int poff = 0;
    #pragma unroll
    for (int j = 0; j < Enum; ++j) if (j < e) poff += (counts[j] + 63) >> 6;
    const int col0 = blockIdx.x * 32;
    const int tid  = threadIdx.x;
    const int lane = tid & 63;
    const int wid  = tid >> 6;

    __shared__ __align__(16) unsigned short Hs[2][8][64][8];   // 16 KB
    __shared__ __align__(16) unsigned short W2s[2][8][32][8];  // 8 KB

    // He staging: chunked layout, wave wid stages kg {2wid, 2wid+1}; fully linear 1 KB chunks
    const unsigned short* hbase = He + (size_t)(poff + c) * 128 * 512 + lane * 8;

    // W2 staging: kg = tid>>5 (8 groups), col = tid&31 (bank-uniform b128 writes)
    const int wkg = tid >> 5;
    const int wcl = tid & 31;
    const float* wsrc = w2 + ((size_t)e * Idim + wkg * 8) * Hdim + col0 + wcl;

    f32x4 acc[2];
    acc[0] = (f32x4)(0.f); acc[1] = (f32x4)(0.f);

    const int NK = Idim / 64; // 16
    float wv[8];
    { // prologue
        #pragma unroll
        for (int kk = 0; kk < 2; ++kk)
            gld_lds16(hbase + (size_t)(wid * 2 + kk) * 512, &Hs[0][wid * 2 + kk][0][0]);
        #pragma unroll
        for (int j = 0; j < 8; ++j) wv[j] = wsrc[(size_t)j * Hdim];
        short8 p;
        #pragma unroll
        for (int j = 0; j < 8; ++j) p[j] = (short)f2bf(wv[j]);
        *(short8*)&W2s[0][wkg][wcl][0] = p;
    }
    __syncthreads();

    for (int ks = 0; ks < NK; ++ks) {
        const int cur = ks & 1, nxt = cur ^ 1;
        if (ks + 1 < NK) {
            #pragma unroll
            for (int kk = 0; kk < 2; ++kk)
                gld_lds16(hbase + (size_t)((ks + 1) * 8 + wid * 2 + kk) * 512,
                          &Hs[nxt][wid * 2 + kk][0][0]);
            const float* wp = wsrc + (size_t)(ks + 1) * 64 * Hdim;
            #pragma unroll
            for (int j = 0; j < 8; ++j) wv[j] = wp[(size_t)j * Hdim];
        }
        #pragma unroll
        for (int ks2 = 0; ks2 < 2; ++ks2) {
            const int kgi = ks2 * 4 + (lane >> 4);
            short8 a  = *(const short8*)&Hs[cur][kgi][wid * 16 + (lane & 15)][0];
            short8 b0 = *(const short8*)&W2s[cur][kgi][(lane & 15)][0];
            short8 b1 = *(const short8*)&W2s[cur][kgi][16 + (lane & 15)][0];
            acc[0] = __builtin_amdgcn_mfma_f32_16x16x32_bf16(a, b0, acc[0], 0, 0, 0);
            acc[1] = __builtin_amdgcn_mfma_f32_16x16x32_bf16(a, b1, acc[1], 0, 0, 0);
        }
        if (ks + 1 < NK) {
            short8 p;
            #pragma unroll
            for (int j = 0; j < 8; ++j) p[j] = (short)f2bf(wv[j]);
            *(short8*)&W2s[nxt][wkg][wcl][0] = p;
        }
        __syncthreads();
    }

    #pragma unroll
    for (int k = 0; k < 4; ++k) {
        int grow = c * 64 + wid * 16 + ((lane >> 4) << 2) + k;
        if (grow < Ne) {
            int   tk = tids[e * Ttok + grow];
            float w  = tws[e * Ttok + grow];
            #pragma unroll
            for (int fc = 0; fc < 2; ++fc) {
                int col = col0 + fc * 16 + (lane & 15);
                atomicAdd(&out[(size_t)tk * Hdim + col], w * acc[fc][k]);
            }
        }
    }
}

extern "C" void kernel_launch(void* const* d_in, const int* in_sizes, int n_in,
                              void* d_out, int out_size, void* d_ws, size_t ws_size,
                              hipStream_t stream)
{
    const float* x    = (const float*)d_in[0];
    const float* gw   = (const float*)d_in[1];
    const float* bias = (const float*)d_in[2];
    const float* w1   = (const float*)d_in[3];
    const float* w3   = (const float*)d_in[4];
    const float* w2   = (const float*)d_in[5];
    float* out = (float*)d_out;

    char* ws = (char*)d_ws;
    int*            counts = (int*)ws;                        // @0       64 B
    int*            tids   = (int*)(ws + 1024);               // @1K      64 KB
    float*          tws    = (float*)(ws + 66560);            // @65K     64 KB
    unsigned short* xbf    = (unsigned short*)(ws + 132096);  // 4 MB
    unsigned short* He     = (unsigned short*)(ws + 4326400); // <= 6.02 MB (47 chunks x 128 KB)

    hipMemsetAsync(counts, 0, Enum * sizeof(int), stream);
    hipMemsetAsync(out, 0, (size_t)Ttok * Hdim * sizeof(float), stream);

    k_router<<<dim3(Ttok), dim3(256), 0, stream>>>(x, gw, bias, xbf, counts, tids, tws);
    k_expert_h<<<dim3(Idim / 32, 16, Enum), dim3(256), 0, stream>>>(xbf, w1, w3, counts, tids, He);
    k_expert_o<<<dim3(Hdim / 32, 16, Enum), dim3(256), 0, stream>>>(He, w2, counts, tids, tws, out);
}